// Round 22
// baseline (134.534 us; speedup 1.0000x reference)
//
#include <hip/hip_runtime.h>
#include <hip/hip_bf16.h>

// MDN NLL, fully fused. N=524288 Dx=128 Dt=64 M=32 K=8.
// R22 = R20 (114.6us best) + WAVE SPECIALIZATION (producer/consumer):
//  - waves 0-7 = full expert each (R18-validated fp8 math: bfrag[2][2][4]
//    =32 regs, 4 MFMAs share one af) -> x-LDS reads HALVE (the dominant
//    pipe; R20's (kx,hh) pairs read identical fragments).
//  - waves 8-15 = producers: all staging (16 staging regs live only here),
//    gate MFMA (waves 8-9), deferred LSE (waves 10-11).
//  - per-iter critical path = max(consumer, producer), not sum.
// Allocation regime: 1024-thr (R20-proven stable; R18's 512-thr spill
// mode avoided). Biases via LDS (R19) to keep VALU-live <= 64.
// Litmus: WRITE_SIZE >50MB => spill returned => revert R20.
// R21 lesson: TILE_R=64 regressed (staging regs + 90KB LDS); stay 32.

#define NN 524288
#define DX 128
#define DT 64
#define MDIM 32
#define KEXP 8
#define TILE_R 32
#define THREADS 1024
#define GRID_MAIN 512
#define TPB 32                   // 16384 tiles / 512 blocks

typedef __bf16 bf16x8 __attribute__((ext_vector_type(8)));
typedef float f32x4 __attribute__((ext_vector_type(4)));
typedef long long i64;

__device__ __forceinline__ bf16x8 cvt8(const f32x4 a, const f32x4 b) {
  bf16x8 r;
  r[0] = (__bf16)a[0]; r[1] = (__bf16)a[1]; r[2] = (__bf16)a[2]; r[3] = (__bf16)a[3];
  r[4] = (__bf16)b[0]; r[5] = (__bf16)b[1]; r[6] = (__bf16)b[2]; r[7] = (__bf16)b[3];
  return r;
}
// pack 8 f32 -> 8 fp8 e4m3 bytes (elem i = byte i) -- validated R18-R21
__device__ __forceinline__ i64 cvt8f8(const f32x4 a, const f32x4 b) {
  int p0 = __builtin_amdgcn_cvt_pk_fp8_f32(a[0], a[1], 0, 0);
  p0 = __builtin_amdgcn_cvt_pk_fp8_f32(a[2], a[3], p0, 1);
  int p1 = __builtin_amdgcn_cvt_pk_fp8_f32(b[0], b[1], 0, 0);
  p1 = __builtin_amdgcn_cvt_pk_fp8_f32(b[2], b[3], p1, 1);
  return (i64)(((unsigned long long)(unsigned)p1 << 32) | (unsigned)p0);
}

#define MFMA16(a, b, c) __builtin_amdgcn_mfma_f32_16x16x32_bf16(a, b, c, 0, 0, 0)
#define MFMA8(a, b, c)  __builtin_amdgcn_mfma_f32_16x16x32_fp8_fp8(a, b, c, 0, 0, 0)

// LDS-only barrier: global loads stay in flight across it (rule 18 fence).
#define B_LDS() do { \
  asm volatile("s_waitcnt lgkmcnt(0)" ::: "memory"); \
  __builtin_amdgcn_s_barrier(); \
  __builtin_amdgcn_sched_barrier(0); } while (0)

#define HL2PI 0.91893853320467274f

__global__ __launch_bounds__(THREADS, 4) void mdn_main(
    const float* __restrict__ x, const float* __restrict__ t,
    const float* __restrict__ y, const float* __restrict__ Wm,
    const float* __restrict__ bm, const float* __restrict__ Wv,
    const float* __restrict__ bv, const float* __restrict__ Wg,
    const float* __restrict__ bg, float* __restrict__ partials,
    float* __restrict__ out_atomic)
{
  __shared__ __align__(16) unsigned char  xs_l[2][TILE_R * DX];   // fp8 2x4KB
  __shared__ __align__(16) unsigned short ts_l[2][TILE_R * DT];   // bf16 2x4KB
  __shared__ __align__(16) float ys_l[2][TILE_R * MDIM];          // f32 2x4KB
  __shared__ __align__(16) unsigned short wg_lds[2 * 64 * 8];     // 2KB
  __shared__ __align__(16) float bm_s[KEXP * MDIM];               // 1KB
  __shared__ __align__(16) float bv_s[KEXP * MDIM];               // 1KB
  __shared__ __align__(16) float llp4[2][TILE_R * 40];            // 10.2KB
  __shared__ __align__(16) float glog[2][TILE_R * 8];             // 2KB
  __shared__ float red_s[16];

  const int tid = threadIdx.x;
  const int lane = tid & 63;
  const int wv = tid >> 6;        // 0..15: 0-7 experts, 8-15 producers
  const int l15 = lane & 15;
  const int lhi = lane >> 4;      // 0..3

  // ---- producer staging geometry (p = tid-512; pre-swizzled source) ----
  const int p = tid - 512;
  const int xr = p >> 4, xsl = p & 15;
  const int x_src = xr * DX + ((xsl ^ (xr & 7)) << 3);       // floats
  const int x_dst = xr * 128 + (xsl << 3);                   // bytes (fp8)
  const int tr = p >> 3, tsl = p & 7;
  const int t_src = tr * DT + ((tsl ^ (tr & 7)) << 3);
  const int t_dst = tr * 128 + (tsl << 4);
  const int uy = p - 256;
  const int yr = uy >> 3, ysl = uy & 7;
  const int y_src = yr * MDIM + ((ysl ^ (yr & 7)) << 2);
  const int y_dst = yr * 128 + (ysl << 4);

  f32x4 sa, sb, ea, eb;
  auto issue = [&](int tile) {
    if (tid < 512) return;
    const float* xp = x + (size_t)tile * (TILE_R * DX) + x_src;
    sa = *(const f32x4*)xp;
    sb = *(const f32x4*)(xp + 4);
    if (p < 256) {
      const float* tp = t + (size_t)tile * (TILE_R * DT) + t_src;
      ea = *(const f32x4*)tp;
      eb = *(const f32x4*)(tp + 4);
    } else {
      ea = *(const f32x4*)(y + (size_t)tile * (TILE_R * MDIM) + y_src);
    }
  };
  auto commit = [&](int buf) {
    if (tid < 512) return;
    *(i64*)((char*)xs_l[buf] + x_dst) = cvt8f8(sa, sb);
    if (p < 256) *(bf16x8*)((char*)ts_l[buf] + t_dst) = cvt8(ea, eb);
    else         *(f32x4*)((char*)ys_l[buf] + y_dst) = ea;
  };

  const int first = blockIdx.x * TPB;
  issue(first);    // tile-0 loads in flight under the weight prologue

  // biases -> LDS (keeps expert VALU-live flat)
  if (tid < KEXP * MDIM) bm_s[tid] = bm[tid];
  else if (tid < 2 * KEXP * MDIM) bv_s[tid - KEXP * MDIM] = bv[tid - KEXP * MDIM];
  f32x4 bgv = {0.f, 0.f, 0.f, 0.f};
  if (wv == 8 || wv == 9) bgv = *(const f32x4*)&bg[(lhi & 1) * 4];

  // fp8 W fragments, FULL expert per wave (R18-validated): [ct][hh][kk],
  // 2 regs each = 32 VGPRs. A row = l15 (m-col in half hh), k = lhi*8+i.
  i64 bfrag[2][2][4];
  if (wv < 8) {
    #pragma unroll
    for (int ct = 0; ct < 2; ++ct) {
      const float* W = (ct ? Wv : Wm) + (size_t)wv * (DX * MDIM);
      #pragma unroll
      for (int hh = 0; hh < 2; ++hh) {
        const int mcol = hh * 16 + l15;
        #pragma unroll
        for (int kk = 0; kk < 4; ++kk) {
          f32x4 wa, wb;
          #pragma unroll
          for (int i = 0; i < 4; ++i) {
            wa[i] = W[(kk * 32 + lhi * 8 + i) * MDIM + mcol];
            wb[i] = W[(kk * 32 + lhi * 8 + 4 + i) * MDIM + mcol];
          }
          bfrag[ct][hh][kk] = cvt8f8(wa, wb);
        }
      }
    }
  }
  // Gate weights -> LDS (one wave; rows >= KEXP zero-padded)
  if (wv == 15) {
    #pragma unroll
    for (int kk = 0; kk < 2; ++kk) {
      bf16x8 tmp;
      #pragma unroll
      for (int i = 0; i < 8; ++i) {
        const int d = kk * 32 + lhi * 8 + i;
        tmp[i] = (__bf16)((l15 < KEXP) ? Wg[d * KEXP + l15] : 0.f);
      }
      *(bf16x8*)((char*)wg_lds + (kk * 64 + lane) * 16) = tmp;
    }
  }

  commit(0);
  B_LDS();        // tile 0 + wg + biases visible

  float loss_acc = 0.f;

  auto do_lse = [&](int pb) {   // waves 10-11; reads llp4/glog[pb]
    const int rr = (wv - 10) * 16 + l15;
    const f32x4 lgv = *(const f32x4*)&glog[pb][rr * 8 + (lhi & 1) * 4];
    const int kb = (lhi & 1) * 4;
    f32x4 a4;
    #pragma unroll
    for (int j = 0; j < 4; ++j) {
      const f32x4 pq = *(const f32x4*)&llp4[pb][rr * 40 + (kb + j) * 4];
      a4[j] = lgv[j] - (pq[0] + pq[1] + pq[2] + pq[3]) - 32.0f * HL2PI;
    }
    float mg = fmaxf(fmaxf(lgv[0], lgv[1]), fmaxf(lgv[2], lgv[3]));
    float ma = fmaxf(fmaxf(a4[0], a4[1]), fmaxf(a4[2], a4[3]));
    mg = fmaxf(mg, __shfl_xor(mg, 16));
    ma = fmaxf(ma, __shfl_xor(ma, 16));
    float eg = __expf(lgv[0] - mg) + __expf(lgv[1] - mg)
             + __expf(lgv[2] - mg) + __expf(lgv[3] - mg);
    float ea2 = __expf(a4[0] - ma) + __expf(a4[1] - ma)
              + __expf(a4[2] - ma) + __expf(a4[3] - ma);
    eg += __shfl_xor(eg, 16);
    ea2 += __shfl_xor(ea2, 16);
    if (lhi == 0)
      loss_acc += (mg + __logf(eg)) - (ma + __logf(ea2));
  };

  for (int it = 0; it < TPB; ++it) {
    const int cur = it & 1;
    issue(first + ((it + 1 < TPB) ? it + 1 : it));   // producers only

    if (wv < 8) {
      // ---- consumer: full-expert fp8 MFMAs + LL partials ----
      const unsigned char* xc = xs_l[cur];
      const float* yc = ys_l[cur];
      #pragma unroll
      for (int rt = 0; rt < 2; ++rt) {
        const int rr = rt * 16 + l15;     // sample (B-col = l15)
        const int r7 = rr & 7;
        f32x4 am0 = *(const f32x4*)&bm_s[wv * MDIM + lhi * 4];
        f32x4 am1 = *(const f32x4*)&bm_s[wv * MDIM + 16 + lhi * 4];
        f32x4 av0 = *(const f32x4*)&bv_s[wv * MDIM + lhi * 4];
        f32x4 av1 = *(const f32x4*)&bv_s[wv * MDIM + 16 + lhi * 4];
        #pragma unroll
        for (int kk = 0; kk < 4; ++kk) {
          const int s = (kk * 4 + lhi) ^ r7;
          const i64 af = *(const i64*)(xc + rr * 128 + s * 8);
          am0 = MFMA8(bfrag[0][0][kk], af, am0);
          am1 = MFMA8(bfrag[0][1][kk], af, am1);
          av0 = MFMA8(bfrag[1][0][kk], af, av0);
          av1 = MFMA8(bfrag[1][1][kk], af, av1);
        }
        // D: col = l15 = sample, row = lhi*4+j = m (hh0) / m+16 (hh1)
        const int s0 = lhi ^ r7, s1 = (4 + lhi) ^ r7;
        const f32x4 y0v = *(const f32x4*)&yc[rr * 32 + s0 * 4];
        const f32x4 y1v = *(const f32x4*)&yc[rr * 32 + s1 * 4];
        float part = 0.f;
        #pragma unroll
        for (int j = 0; j < 4; ++j) {
          const float d0 = y0v[j] - am0[j];
          const float d1 = y1v[j] - am1[j];
          part += d0 * d0 * (0.5f * __expf(-av0[j])) + 0.5f * av0[j];
          part += d1 * d1 * (0.5f * __expf(-av1[j])) + 0.5f * av1[j];
        }
        llp4[cur][rr * 40 + wv * 4 + lhi] = part;   // no shuffles
      }
    } else {
      // ---- producers: deferred LSE (10-11), gate (8-9), commit (all) ----
      if (it && (wv == 10 || wv == 11)) do_lse(cur ^ 1);
      if (wv == 8 || wv == 9) {
        const int rr = (wv - 8) * 16 + l15;
        const int r7 = rr & 7;
        f32x4 g = {0.f, 0.f, 0.f, 0.f};
        #pragma unroll
        for (int kk = 0; kk < 2; ++kk) {
          const int s = (kk * 4 + lhi) ^ r7;
          const bf16x8 tf = *(const bf16x8*)((const char*)ts_l[cur] + rr * 128 + s * 16);
          const bf16x8 wf = *(const bf16x8*)((const char*)wg_lds + (kk * 64 + lane) * 16);
          g = MFMA16(wf, tf, g);
        }
        if (lhi < 2) {
          f32x4 lg;
          #pragma unroll
          for (int j = 0; j < 4; ++j) lg[j] = g[j] + bgv[j];
          *(f32x4*)&glog[cur][rr * 8 + lhi * 4] = lg;
        }
      }
      commit(cur ^ 1);
    }

    B_LDS();           // the ONE barrier: llp4/glog[cur] + stages visible
  }
  if (wv == 10 || wv == 11) do_lse((TPB - 1) & 1);

  // block reduction of loss
  loss_acc += __shfl_xor(loss_acc, 1);
  loss_acc += __shfl_xor(loss_acc, 2);
  loss_acc += __shfl_xor(loss_acc, 4);
  loss_acc += __shfl_xor(loss_acc, 8);
  loss_acc += __shfl_xor(loss_acc, 16);
  loss_acc += __shfl_xor(loss_acc, 32);
  if (lane == 0) red_s[wv] = loss_acc;
  __syncthreads();
  if (tid == 0) {
    float s = 0.f;
    #pragma unroll
    for (int w = 0; w < 16; ++w) s += red_s[w];
    if (partials) partials[blockIdx.x] = s;
    else atomicAdd(out_atomic, s);
  }
}

__global__ void mdn_reg(const float* __restrict__ Wm, const float* __restrict__ Wv,
                        const float* __restrict__ Wg, float* __restrict__ partials,
                        float* __restrict__ out_atomic)
{
  __shared__ float red[4];
  const int gid = blockIdx.x * 256 + threadIdx.x;
  const int stride = 64 * 256;
  float s = 0.f;
  for (int i = gid; i < DX * MDIM * KEXP; i += stride) { float w = Wm[i]; s += w * w; }
  for (int i = gid; i < DX * MDIM * KEXP; i += stride) { float w = Wv[i]; s += w * w; }
  for (int i = gid; i < DT * KEXP; i += stride)        { float w = Wg[i]; s += w * w; }
  s += __shfl_xor(s, 1);
  s += __shfl_xor(s, 2);
  s += __shfl_xor(s, 4);
  s += __shfl_xor(s, 8);
  s += __shfl_xor(s, 16);
  s += __shfl_xor(s, 32);
  if ((threadIdx.x & 63) == 0) red[threadIdx.x >> 6] = s;
  __syncthreads();
  if (threadIdx.x == 0) {
    float b = red[0] + red[1] + red[2] + red[3];
    if (partials) partials[GRID_MAIN + blockIdx.x] = b;
    else atomicAdd(out_atomic, b);
  }
}

__global__ void mdn_final(const float* __restrict__ partials, float* __restrict__ out)
{
  __shared__ float red[4];
  float s = 0.f;
  for (int i = threadIdx.x; i < GRID_MAIN + 64; i += 256) s += partials[i];
  s += __shfl_xor(s, 1);
  s += __shfl_xor(s, 2);
  s += __shfl_xor(s, 4);
  s += __shfl_xor(s, 8);
  s += __shfl_xor(s, 16);
  s += __shfl_xor(s, 32);
  if ((threadIdx.x & 63) == 0) red[threadIdx.x >> 6] = s;
  __syncthreads();
  if (threadIdx.x == 0) out[0] = red[0] + red[1] + red[2] + red[3];
}

extern "C" void kernel_launch(void* const* d_in, const int* in_sizes, int n_in,
                              void* d_out, int out_size, void* d_ws, size_t ws_size,
                              hipStream_t stream)
{
  const float* x  = (const float*)d_in[0];
  const float* t  = (const float*)d_in[1];
  const float* y  = (const float*)d_in[2];
  const float* Wm = (const float*)d_in[3];
  const float* bm = (const float*)d_in[4];
  const float* Wv = (const float*)d_in[5];
  const float* bv = (const float*)d_in[6];
  const float* Wg = (const float*)d_in[7];
  const float* bg = (const float*)d_in[8];
  float* out = (float*)d_out;

  if (ws_size >= (GRID_MAIN + 64) * sizeof(float)) {
    float* partials = (float*)d_ws;
    mdn_main<<<GRID_MAIN, THREADS, 0, stream>>>(x, t, y, Wm, bm, Wv, bv, Wg, bg,
                                                partials, nullptr);
    mdn_reg<<<64, 256, 0, stream>>>(Wm, Wv, Wg, partials, nullptr);
    mdn_final<<<1, 256, 0, stream>>>(partials, out);
  } else {
    hipMemsetAsync(out, 0, sizeof(float), stream);
    mdn_main<<<GRID_MAIN, THREADS, 0, stream>>>(x, t, y, Wm, bm, Wv, bv, Wg, bg,
                                                nullptr, out);
    mdn_reg<<<64, 256, 0, stream>>>(Wm, Wv, Wg, nullptr, out);
  }
}